// Round 7
// baseline (216.130 us; speedup 1.0000x reference)
//
#include <hip/hip_runtime.h>
#include <math.h>

// z:  (2,1,256,256,64)  idx = b*4194304 + x*16384 + y*64 + k
// tg: (2,3,256,256,64)  idx = b*12582912 + c*4194304 + x*16384 + y*64 + k
//
// Single-phase loads: all 37 float4 global loads (z neighborhood + 12 b-corner
// groups) issue before any compute -> one vmcnt drain per thread instead of
// 4-5 serialized phases. Interior blocks (60/64 per dim) use constant offsets,
// no clamps. Div math prefix-factored (telescoping g/h arrays).
// LDS only for the final reduction (8.2 KB). XCD swizzle for L2 halo reuse.
//
// ws layout (floats), 32 slices x 258:
//   sl[p*258 + 0]=smooth, +1=div, +2+b*64+k = s1, +130+b*64+k = s2

#define XSF 16384

__global__ __launch_bounds__(512) void zero_ws_kernel(float* ws) {
    for (int i = threadIdx.x; i < 32 * 258; i += 512) ws[i] = 0.0f;
}

__device__ __forceinline__ void ld5(float* a, const float* p, int d4) {
    float4 x = *(const float4*)p;
    float4 y = *(const float4*)(p + d4);
    a[0] = x.x; a[1] = x.y; a[2] = x.z; a[3] = x.w; a[4] = y.x;
}

__global__ __launch_bounds__(256, 3) void fused_loss_kernel(
    const float* __restrict__ zin, const float* __restrict__ tg,
    float* __restrict__ ws)
{
    __shared__ float r1[1024];
    __shared__ float r2[1024];
    __shared__ float rsc[4][2];

    const int tid  = threadIdx.x;
    const int lane = tid & 63;
    const int w    = tid >> 6;

    // XCD swizzle: give each XCD a contiguous tile range so halos hit its L2.
    const int virt = ((blockIdx.x & 7) << 10) | (blockIdx.x >> 3);
    const int bb   = virt >> 12;
    const int rest = virt & 4095;
    const int x0 = ((rest >> 6) & 63) << 2;
    const int y0 = (rest & 63) << 2;

    const int c  = tid >> 4;
    const int kq = tid & 15;
    const int cx = c & 3, cy = c >> 2;
    const int xg = x0 + cx, yg = y0 + cy;
    const int k0 = kq << 2;

    const bool interior = (x0 >= 4) && (x0 <= 248) && (y0 >= 4) && (y0 <= 248);

    const int oC = xg * XSF + yg * 64 + k0;
    int oE, oW, oN, oS, oNE, d4;
    if (interior) {
        oE = oC + XSF; oW = oC - XSF; oN = oC + 64; oS = oC - 64; oNE = oC + XSF + 64;
        d4 = 4;   // k-edge garbage is masked by (k0+e)<63 predicates; in-bounds.
    } else {
        const int xE = (xg < 255) ? xg + 1 : 255;
        const int xW = (xg > 0)   ? xg - 1 : 0;
        const int yN = (yg < 255) ? yg + 1 : 255;
        const int yS = (yg > 0)   ? yg - 1 : 0;
        oE  = xE * XSF + yg * 64 + k0;
        oW  = xW * XSF + yg * 64 + k0;
        oN  = xg * XSF + yN * 64 + k0;
        oS  = xg * XSF + yS * 64 + k0;
        oNE = xE * XSF + yN * 64 + k0;
        d4  = (kq < 15) ? 4 : 0;    // don't read past the allocation at the far corner
    }

    const float* zg  = zin + ((size_t)bb << 22);
    const float* bxg = tg  + ((size_t)(bb * 3) << 22);
    const float* byg = bxg + (1u << 22);
    const float* bzg = byg + (1u << 22);

    // ================= ALL LOADS =================
    float zcv[7];
    {
        int km = (k0 >= 4) ? -4 : 0;
        float4 m = *(const float4*)&zg[oC + km];
        float4 a = *(const float4*)&zg[oC];
        float4 b = *(const float4*)&zg[oC + d4];
        zcv[0] = m.w; zcv[1] = a.x; zcv[2] = a.y; zcv[3] = a.z; zcv[4] = a.w;
        zcv[5] = b.x; zcv[6] = b.y;
    }
    float zEv[5], zWv[5], zNv[5], zSv[5], zNEv[5];
    ld5(zEv,  &zg[oE],  d4);
    ld5(zWv,  &zg[oW],  d4);
    ld5(zNv,  &zg[oN],  d4);
    ld5(zSv,  &zg[oS],  d4);
    ld5(zNEv, &zg[oNE], d4);

    float X00[5], X10[5], X01[5], X11[5];
    ld5(X00, &bxg[oC], d4);  ld5(X10, &bxg[oE], d4);
    ld5(X01, &bxg[oN], d4);  ld5(X11, &bxg[oNE], d4);
    float Y00[5], Y10[5], Y01[5], Y11[5];
    ld5(Y00, &byg[oC], d4);  ld5(Y10, &byg[oE], d4);
    ld5(Y01, &byg[oN], d4);  ld5(Y11, &byg[oNE], d4);
    float Z00[5], Z10[5], Z01[5], Z11[5];
    ld5(Z00, &bzg[oC], d4);  ld5(Z10, &bzg[oE], d4);
    ld5(Z01, &bzg[oN], d4);  ld5(Z11, &bzg[oNE], d4);

    // ================= COMPUTE =================
    float dz0[4], dzE[4], dzN[4], dzNE[4];
    #pragma unroll
    for (int e = 0; e < 4; ++e) {
        dz0[e]  = zcv[e + 2] - zcv[e + 1];
        dzE[e]  = zEv[e + 1] - zEv[e];
        dzN[e]  = zNv[e + 1] - zNv[e];
        dzNE[e] = zNEv[e + 1] - zNEv[e];
    }
    float s1a[4], s2a[4];
    #pragma unroll
    for (int e = 0; e < 4; ++e) {
        bool kok = (k0 + e) < 63;
        s1a[e] = kok ? dz0[e] : 0.0f;
        s2a[e] = kok ? dz0[e] * dz0[e] : 0.0f;
    }

    // smooth (z only; frees zWv/zSv afterwards)
    float sm = 0.0f;
    if (xg >= 1 && xg <= 254 && yg >= 1 && yg <= 254) {
        #pragma unroll
        for (int e = 0; e < 4; ++e) {
            int k = k0 + e;
            if (k >= 1 && k <= 61) {
                float dzm = zcv[e + 1] - zcv[e];
                float dzp = zcv[e + 3] - zcv[e + 2];
                float dzw = zWv[e + 1] - zWv[e];
                float dzs = zSv[e + 1] - zSv[e];
                float lap = 6.0f * dz0[e] * dz0[e]
                          - dzw * dzw - dzE[e] * dzE[e]
                          - dzs * dzs - dzN[e] * dzN[e]
                          - dzm * dzm - dzp * dzp;
                sm += lap * lap;
            }
        }
    }

    float dv = 0.0f;
    if (xg < 255 && yg < 255) {
        float dCE[5], dCN[5], dENE[5], dNNE[5];
        #pragma unroll
        for (int j = 0; j < 5; ++j) {
            dCE[j]  = zcv[j + 1] - zEv[j];
            dCN[j]  = zcv[j + 1] - zNv[j];
            dENE[j] = zEv[j] - zNEv[j];
            dNNE[j] = zNv[j] - zNEv[j];
        }
        float sxp[4], sxm[4], syp[4], sym[4];
        #pragma unroll
        for (int e = 0; e < 4; ++e) {
            float aC = fabsf(dz0[e]),  aE  = fabsf(dzE[e]);
            float aN = fabsf(dzN[e]),  aNE = fabsf(dzNE[e]);
            sxp[e] = aE + aNE;  sxm[e] = aC + aN;
            syp[e] = aN + aNE;  sym[e] = aC + aE;
        }

        const float c6 = 1.0f / 6.0f;
        float num[4], den[4];

        // -- bx --  (telescoping g)
        {
            float qx[5], px2[5], g[5];
            #pragma unroll
            for (int j = 0; j < 5; ++j) {
                qx[j]  = X10[j] + X11[j];
                px2[j] = X00[j] + X01[j];
                g[j]   = (qx[j] + X00[j]) * dCE[j] + (qx[j] + X01[j]) * dNNE[j];
            }
            #pragma unroll
            for (int e = 0; e < 4; ++e) {
                float qq = qx[e] + qx[e + 1], pp = px2[e] + px2[e + 1];
                num[e] = 0.125f * (qq * sxp[e] - pp * sxm[e]) + c6 * (g[e + 1] - g[e]);
                float s = qq + pp;
                den[e] = s * s;
            }
        }
        // -- by --  (telescoping h)
        {
            float qy[5], py2[5], h[5];
            #pragma unroll
            for (int j = 0; j < 5; ++j) {
                qy[j]  = Y01[j] + Y11[j];
                py2[j] = Y00[j] + Y10[j];
                h[j]   = (qy[j] + Y10[j]) * dENE[j] + (qy[j] + Y00[j]) * dCN[j];
            }
            #pragma unroll
            for (int e = 0; e < 4; ++e) {
                float qq = qy[e] + qy[e + 1], pp = py2[e] + py2[e + 1];
                num[e] += 0.125f * (qq * syp[e] - pp * sym[e]) + c6 * (h[e + 1] - h[e]);
                float s = qq + pp;
                den[e] += s * s;
            }
        }
        // -- bz --
        {
            float sz[5];
            #pragma unroll
            for (int j = 0; j < 5; ++j)
                sz[j] = Z00[j] + Z10[j] + Z01[j] + Z11[j];
            #pragma unroll
            for (int e = 0; e < 4; ++e) {
                num[e] += 0.25f * (sz[e + 1] - sz[e]);
                float s = sz[e] + sz[e + 1];
                den[e] += s * s;
            }
        }
        #pragma unroll
        for (int e = 0; e < 4; ++e) {
            if ((k0 + e) < 63) {
                float d = den[e] * 0.015625f + 1e-10f;
                dv += num[e] * num[e] * __builtin_amdgcn_rcpf(d);
            }
        }
    }

    // ================= REDUCTION =================
    #pragma unroll
    for (int off = 32; off > 0; off >>= 1) {
        sm += __shfl_down(sm, off, 64);
        dv += __shfl_down(dv, off, 64);
    }

    { float4 v; v.x = s1a[0]; v.y = s1a[1]; v.z = s1a[2]; v.w = s1a[3];
      *(float4*)&r1[tid << 2] = v; }
    { float4 v; v.x = s2a[0]; v.y = s2a[1]; v.z = s2a[2]; v.w = s2a[3];
      *(float4*)&r2[tid << 2] = v; }
    if (lane == 0) { rsc[w][0] = sm; rsc[w][1] = dv; }
    __syncthreads();

    if (tid < 64) {
        float a = 0.0f, b2 = 0.0f;
        #pragma unroll
        for (int cc = 0; cc < 16; ++cc) {
            a  += r1[cc * 64 + tid];
            b2 += r2[cc * 64 + tid];
        }
        float* sl = ws + (blockIdx.x & 31) * 258;
        if (tid < 63) {
            atomicAdd(&sl[2 + bb * 64 + tid],   a);
            atomicAdd(&sl[130 + bb * 64 + tid], b2);
        }
        if (tid == 0) atomicAdd(&sl[0], rsc[0][0] + rsc[1][0] + rsc[2][0] + rsc[3][0]);
        if (tid == 1) atomicAdd(&sl[1], rsc[0][1] + rsc[1][1] + rsc[2][1] + rsc[3][1]);
    }
}

__global__ __launch_bounds__(128) void finalize_kernel(const float* __restrict__ ws,
                                                       float* __restrict__ out)
{
    __shared__ double red[128];
    const int t = threadIdx.x;
    double stdv = 0.0;
    {
        int k = t & 63, bb = t >> 6;
        if (k < 63) {
            double s1 = 0.0, s2 = 0.0;
            for (int p = 0; p < 32; ++p) {
                s1 += (double)ws[p * 258 + 2 + bb * 64 + k];
                s2 += (double)ws[p * 258 + 130 + bb * 64 + k];
            }
            const double N = 65536.0;
            double var = (s2 - s1 * s1 / N) / (N - 1.0);
            stdv = sqrt(var > 0.0 ? var : 0.0);
        }
    }
    red[t] = stdv;
    __syncthreads();
    for (int off = 64; off > 0; off >>= 1) {
        if (t < off) red[t] += red[t + off];
        __syncthreads();
    }
    if (t == 0) {
        double smt = 0.0, dvt = 0.0;
        for (int p = 0; p < 32; ++p) {
            smt += (double)ws[p * 258 + 0];
            dvt += (double)ws[p * 258 + 1];
        }
        double loss_std    = red[0] / 126.0;
        double loss_smooth = smt / (2.0 * 254.0 * 254.0 * 61.0);
        double loss_div    = dvt / (2.0 * 255.0 * 255.0 * 63.0);
        out[0] = (float)(loss_div * 1e9);
        out[1] = (float)(loss_smooth * 10.0 + loss_std * 100.0);
    }
}

extern "C" void kernel_launch(void* const* d_in, const int* in_sizes, int n_in,
                              void* d_out, int out_size, void* d_ws, size_t ws_size,
                              hipStream_t stream) {
    const float* z  = (const float*)d_in[0];   // outputs (2,1,256,256,64)
    const float* tg = (const float*)d_in[1];   // targets (2,3,256,256,64)
    float* out = (float*)d_out;
    float* ws  = (float*)d_ws;

    zero_ws_kernel<<<1, 512, 0, stream>>>(ws);
    // 64x64 tiles x 2 batches = 8192 blocks
    fused_loss_kernel<<<8192, 256, 0, stream>>>(z, tg, ws);
    finalize_kernel<<<1, 128, 0, stream>>>(ws, out);
}

// Round 8
// 213.720 us; speedup vs baseline: 1.0113x; 1.0113x over previous
//
#include <hip/hip_runtime.h>
#include <math.h>

// z:  (2,1,256,256,64)  idx = b*4194304 + x*16384 + y*64 + k
// tg: (2,3,256,256,64)  idx = b*12582912 + c*4194304 + x*16384 + y*64 + k
//
// k-rolling: block = 8x8 cells, thread = (cell, kq), kq quarter owns k in
// [16kq,16kq+16). 4 float4 chunks per array with loop-carried 5-wide windows:
// the k+1 shift is the rolling carry -> ~17/16 load amplification (vs 8/5 for
// the old ld5 scheme). Div telescoping sums rolled as scalars. Per-(b,k) std
// partials via conflict-free LDS [kslot][cell] scatter (kslot partition by kq
// is exact), block-reduced after one barrier.
//
// ws layout (floats), 32 slices x 258:
//   sl[p*258+0]=smooth, +1=div, +2+b*64+k=s1, +130+b*64+k=s2

#define XSF 16384

__global__ __launch_bounds__(512) void zero_ws_kernel(float* ws) {
    for (int i = threadIdx.x; i < 32 * 258; i += 512) ws[i] = 0.0f;
}

__global__ __launch_bounds__(256) void fused_loss_kernel(
    const float* __restrict__ zin, const float* __restrict__ tg,
    float* __restrict__ ws)
{
    __shared__ float S1[64 * 65];   // [kslot][cell], stride 65 de-phases banks
    __shared__ float S2[64 * 65];
    __shared__ float rsc[4][2];

    const int tid  = threadIdx.x;
    const int lane = tid & 63;
    const int w    = tid >> 6;

    // XCD swizzle: contiguous tile range per XCD (2048 blocks = 8 x 256).
    const int virt = ((blockIdx.x & 7) << 8) | (blockIdx.x >> 3);
    const int bb   = virt >> 10;
    const int rest = virt & 1023;
    const int x0 = ((rest >> 5) & 31) << 3;
    const int y0 = (rest & 31) << 3;

    const int cell = tid >> 2;
    const int kq   = tid & 3;
    const int cx = cell & 7, cy = cell >> 3;
    const int xg = x0 + cx, yg = y0 + cy;
    const int K  = kq << 4;

    const int xE = (xg < 255) ? xg + 1 : 255;
    const int xW = (xg > 0)   ? xg - 1 : 0;
    const int yN = (yg < 255) ? yg + 1 : 255;
    const int yS = (yg > 0)   ? yg - 1 : 0;

    const int oC  = xg * XSF + yg * 64 + K;
    const int oE  = xE * XSF + yg * 64 + K;
    const int oWo = xW * XSF + yg * 64 + K;
    const int oN  = xg * XSF + yN * 64 + K;
    const int oS  = xg * XSF + yS * 64 + K;
    const int oNE = xE * XSF + yN * 64 + K;

    const float* zg  = zin + ((size_t)bb << 22);
    const float* bxg = tg  + ((size_t)(bb * 3) << 22);
    const float* byg = bxg + (1u << 22);
    const float* bzg = byg + (1u << 22);

    const float* pzC  = zg + oC;   const float* pzE  = zg + oE;
    const float* pzW  = zg + oWo;  const float* pzN  = zg + oN;
    const float* pzS  = zg + oS;   const float* pzNE = zg + oNE;
    const float* pX00 = bxg + oC;  const float* pX10 = bxg + oE;
    const float* pX01 = bxg + oN;  const float* pX11 = bxg + oNE;
    const float* pY00 = byg + oC;  const float* pY10 = byg + oE;
    const float* pY01 = byg + oN;  const float* pY11 = byg + oNE;
    const float* pZ00 = bzg + oC;  const float* pZ10 = bzg + oE;
    const float* pZ01 = bzg + oN;  const float* pZ11 = bzg + oNE;

    const int om1 = kq ? -1 : 0;   // carry element K-1 (clamped for kq=0, masked)

    float wzC[5], wzE[5], wzW[5], wzN[5], wzS[5], wzNE[5];
    float wX00[5], wX10[5], wX01[5], wX11[5];
    float wY00[5], wY10[5], wY01[5], wY11[5];
    float wZ00[5], wZ10[5], wZ01[5], wZ11[5];

    // prologue: carries (element K-1)
    wzC[4]  = pzC[om1];  wzE[4]  = pzE[om1];  wzW[4] = pzW[om1];
    wzN[4]  = pzN[om1];  wzS[4]  = pzS[om1];  wzNE[4] = pzNE[om1];
    wX00[4] = pX00[om1]; wX10[4] = pX10[om1]; wX01[4] = pX01[om1]; wX11[4] = pX11[om1];
    wY00[4] = pY00[om1]; wY10[4] = pY10[om1]; wY01[4] = pY01[om1]; wY11[4] = pY11[om1];
    wZ00[4] = pZ00[om1]; wZ10[4] = pZ10[om1]; wZ01[4] = pZ01[om1]; wZ11[4] = pZ11[om1];

    // rolled scalars at index kd = K-1
    float dCE_p  = wzC[4] - wzE[4],  dCN_p  = wzC[4] - wzN[4];
    float dENE_p = wzE[4] - wzNE[4], dNNE_p = wzN[4] - wzNE[4];
    float qx_p = wX10[4] + wX11[4], px_p = wX00[4] + wX01[4];
    float g_p  = (qx_p + wX00[4]) * dCE_p + (qx_p + wX01[4]) * dNNE_p;
    float qy_p = wY01[4] + wY11[4], py_p = wY00[4] + wY10[4];
    float h_p  = (qy_p + wY10[4]) * dENE_p + (qy_p + wY00[4]) * dCN_p;
    float sz_p = wZ00[4] + wZ10[4] + wZ01[4] + wZ11[4];

    float pdzE = 0.f, pdzW = 0.f, pdzN = 0.f, pdzS = 0.f, pd2c = 0.f, ppd2c = 0.f;

    const bool smxy = (xg >= 1) && (xg <= 254) && (yg >= 1) && (yg <= 254);
    const bool dvxy = (xg < 255) && (yg < 255);
    const float c6 = 1.0f / 6.0f;

    float sm = 0.f, dv = 0.f;

#define LOADCHUNK(n, p) { float4 _v = *(const float4*)((p) + 4*c); \
    n[0] = n[4]; n[1] = _v.x; n[2] = _v.y; n[3] = _v.z; n[4] = _v.w; }

    #pragma unroll
    for (int c = 0; c < 4; ++c) {
        LOADCHUNK(wzC,  pzC)   LOADCHUNK(wzE,  pzE)   LOADCHUNK(wzW,  pzW)
        LOADCHUNK(wzN,  pzN)   LOADCHUNK(wzS,  pzS)   LOADCHUNK(wzNE, pzNE)
        LOADCHUNK(wX00, pX00)  LOADCHUNK(wX10, pX10)  LOADCHUNK(wX01, pX01)
        LOADCHUNK(wX11, pX11)  LOADCHUNK(wY00, pY00)  LOADCHUNK(wY10, pY10)
        LOADCHUNK(wY01, pY01)  LOADCHUNK(wY11, pY11)  LOADCHUNK(wZ00, pZ00)
        LOADCHUNK(wZ10, pZ10)  LOADCHUNK(wZ01, pZ01)  LOADCHUNK(wZ11, pZ11)

        #pragma unroll
        for (int e = 0; e < 4; ++e) {
            // dz at kd = K+4c+e-1
            float dzC  = wzC[e+1]  - wzC[e];
            float dzE  = wzE[e+1]  - wzE[e];
            float dzN  = wzN[e+1]  - wzN[e];
            float dzNE = wzNE[e+1] - wzNE[e];
            float dzW  = wzW[e+1]  - wzW[e];
            float dzS  = wzS[e+1]  - wzS[e];
            float d2c  = dzC * dzC;

            const int t4 = 4 * c + e;
            const bool kdok = (t4 > 0) || (kq > 0);

            // std scatter to LDS (kslot = kd+1 = K+t4; exact per-thread partition)
            S1[(K + t4) * 65 + cell] = kdok ? dzC : 0.f;
            S2[(K + t4) * 65 + cell] = kdok ? d2c : 0.f;

            // rolled "+1" values at kd+1
            float dCE1  = wzC[e+1] - wzE[e+1];
            float dCN1  = wzC[e+1] - wzN[e+1];
            float dENE1 = wzE[e+1] - wzNE[e+1];
            float dNNE1 = wzN[e+1] - wzNE[e+1];
            float qx1 = wX10[e+1] + wX11[e+1];
            float px1 = wX00[e+1] + wX01[e+1];
            float g1  = (qx1 + wX00[e+1]) * dCE1 + (qx1 + wX01[e+1]) * dNNE1;
            float qy1 = wY01[e+1] + wY11[e+1];
            float py1 = wY00[e+1] + wY10[e+1];
            float h1  = (qy1 + wY10[e+1]) * dENE1 + (qy1 + wY00[e+1]) * dCN1;
            float sz1 = wZ00[e+1] + wZ10[e+1] + wZ01[e+1] + wZ11[e+1];

            if (kdok && dvxy) {
                float aC = fabsf(dzC), aE = fabsf(dzE), aN = fabsf(dzN), aNE = fabsf(dzNE);
                float num = 0.125f * ((qx_p + qx1) * (aE + aNE) - (px_p + px1) * (aC + aN)
                                    + (qy_p + qy1) * (aN + aNE) - (py_p + py1) * (aC + aE))
                          + c6 * ((g1 - g_p) + (h1 - h_p)) + 0.25f * (sz1 - sz_p);
                float sbx = qx_p + qx1 + px_p + px1;
                float sby = qy_p + qy1 + py_p + py1;
                float sbz = sz_p + sz1;
                float den = 0.015625f * (sbx * sbx + sby * sby + sbz * sbz) + 1e-10f;
                dv += num * num * __builtin_amdgcn_rcpf(den);
            }

            // smooth at kl = kd-1 = K+t4-2 (needs d2c[kl+1] = current d2c)
            {
                const bool klok = (t4 >= 2) && ((kq > 0) || (t4 >= 3));
                if (klok && smxy) {
                    float lap = 6.f * pd2c - pdzW * pdzW - pdzE * pdzE
                              - pdzS * pdzS - pdzN * pdzN - ppd2c - d2c;
                    sm += lap * lap;
                }
            }
            // rolls
            ppd2c = pd2c; pd2c = d2c;
            pdzE = dzE; pdzW = dzW; pdzN = dzN; pdzS = dzS;
            qx_p = qx1; px_p = px1; g_p = g1;
            qy_p = qy1; py_p = py1; h_p = h1; sz_p = sz1;
        }
    }
#undef LOADCHUNK

    // epilogue: lap at kl = K+14, K+15 (kq<3; kq=3 slots are k=62,63 -> masked)
    {
        const int epi = (kq < 3) ? 16 : 12;           // element K+16 (or dummy)
        float2 zc2 = *(const float2*)(pzC + epi);
        float zE16 = pzE[epi], zW16 = pzW[epi], zN16 = pzN[epi], zS16 = pzS[epi];
        float dzC15 = zc2.x - wzC[4];
        float dzC16 = zc2.y - zc2.x;
        float dzE15 = zE16 - wzE[4], dzW15 = zW16 - wzW[4];
        float dzN15 = zN16 - wzN[4], dzS15 = zS16 - wzS[4];
        if ((kq < 3) && smxy) {
            float d2c15 = dzC15 * dzC15;
            float lap = 6.f * pd2c - pdzW * pdzW - pdzE * pdzE
                      - pdzS * pdzS - pdzN * pdzN - ppd2c - d2c15;
            sm += lap * lap;
            float lap2 = 6.f * d2c15 - dzE15 * dzE15 - dzW15 * dzW15
                       - dzS15 * dzS15 - dzN15 * dzN15 - pd2c - dzC16 * dzC16;
            sm += lap2 * lap2;
        }
    }

    // ---- reductions ----
    #pragma unroll
    for (int off = 32; off > 0; off >>= 1) {
        sm += __shfl_down(sm, off, 64);
        dv += __shfl_down(dv, off, 64);
    }
    if (lane == 0) { rsc[w][0] = sm; rsc[w][1] = dv; }
    __syncthreads();

    {
        const int kslot = tid >> 2, part = tid & 3;
        const float* a1 = &S1[kslot * 65 + part * 16];
        const float* a2 = &S2[kslot * 65 + part * 16];
        float s1 = 0.f, s2 = 0.f;
        #pragma unroll
        for (int i = 0; i < 16; ++i) { s1 += a1[i]; s2 += a2[i]; }
        s1 += __shfl_down(s1, 2, 64); s1 += __shfl_down(s1, 1, 64);
        s2 += __shfl_down(s2, 2, 64); s2 += __shfl_down(s2, 1, 64);
        float* sl = ws + (blockIdx.x & 31) * 258;
        if (part == 0 && kslot >= 1) {
            atomicAdd(&sl[2 + bb * 64 + (kslot - 1)],   s1);
            atomicAdd(&sl[130 + bb * 64 + (kslot - 1)], s2);
        }
        if (tid == 0) atomicAdd(&sl[0], rsc[0][0] + rsc[1][0] + rsc[2][0] + rsc[3][0]);
        if (tid == 1) atomicAdd(&sl[1], rsc[0][1] + rsc[1][1] + rsc[2][1] + rsc[3][1]);
    }
}

__global__ __launch_bounds__(128) void finalize_kernel(const float* __restrict__ ws,
                                                       float* __restrict__ out)
{
    __shared__ double red[128];
    const int t = threadIdx.x;
    double stdv = 0.0;
    {
        int k = t & 63, bb = t >> 6;
        if (k < 63) {
            double s1 = 0.0, s2 = 0.0;
            for (int p = 0; p < 32; ++p) {
                s1 += (double)ws[p * 258 + 2 + bb * 64 + k];
                s2 += (double)ws[p * 258 + 130 + bb * 64 + k];
            }
            const double N = 65536.0;
            double var = (s2 - s1 * s1 / N) / (N - 1.0);
            stdv = sqrt(var > 0.0 ? var : 0.0);
        }
    }
    red[t] = stdv;
    __syncthreads();
    for (int off = 64; off > 0; off >>= 1) {
        if (t < off) red[t] += red[t + off];
        __syncthreads();
    }
    if (t == 0) {
        double smt = 0.0, dvt = 0.0;
        for (int p = 0; p < 32; ++p) {
            smt += (double)ws[p * 258 + 0];
            dvt += (double)ws[p * 258 + 1];
        }
        double loss_std    = red[0] / 126.0;
        double loss_smooth = smt / (2.0 * 254.0 * 254.0 * 61.0);
        double loss_div    = dvt / (2.0 * 255.0 * 255.0 * 63.0);
        out[0] = (float)(loss_div * 1e9);
        out[1] = (float)(loss_smooth * 10.0 + loss_std * 100.0);
    }
}

extern "C" void kernel_launch(void* const* d_in, const int* in_sizes, int n_in,
                              void* d_out, int out_size, void* d_ws, size_t ws_size,
                              hipStream_t stream) {
    const float* z  = (const float*)d_in[0];   // outputs (2,1,256,256,64)
    const float* tg = (const float*)d_in[1];   // targets (2,3,256,256,64)
    float* out = (float*)d_out;
    float* ws  = (float*)d_ws;

    zero_ws_kernel<<<1, 512, 0, stream>>>(ws);
    // 32x32 tiles x 2 batches = 2048 blocks of 256 threads (8x8 cells x 4 kq)
    fused_loss_kernel<<<2048, 256, 0, stream>>>(z, tg, ws);
    finalize_kernel<<<1, 128, 0, stream>>>(ws, out);
}

// Round 9
// 207.620 us; speedup vs baseline: 1.0410x; 1.0294x over previous
//
#include <hip/hip_runtime.h>
#include <math.h>

// z:  (2,1,256,256,64)  idx = b*4194304 + x*16384 + y*64 + k
// tg: (2,3,256,256,64)  idx = b*12582912 + c*4194304 + x*16384 + y*64 + k
//
// Full LDS staging, conflict-free: every staged row has stride 68 floats
// (68%32=4 -> neighbor rows staggered 4 banks; rows used together in one
// wave instruction land at shifts {0,8,16,24} or {0,20,8,28} -> balanced,
// no conflicts). Block = 4x4 cells, thread = (cell, k-quad). One barrier.
// All compute windows from LDS (k+1 shift = +4B, no shuffles). Div math
// prefix-factored (R7 telescoping). LDS reused for the std reduction.
//
// ws layout (floats), 32 slices x 258:
//   sl[p*258+0]=smooth, +1=div, +2+b*64+k=s1, +130+b*64+k=s2

#define RS 68               // row stride in floats

__global__ __launch_bounds__(512) void zero_ws_kernel(float* ws) {
    for (int i = threadIdx.x; i < 32 * 258; i += 512) ws[i] = 0.0f;
}

__device__ __forceinline__ void ld5(float* a, const float* p) {
    float4 x = *(const float4*)p;
    a[0] = x.x; a[1] = x.y; a[2] = x.z; a[3] = x.w; a[4] = p[4];
}

__global__ __launch_bounds__(256) void fused_loss_kernel(
    const float* __restrict__ zin, const float* __restrict__ tg,
    float* __restrict__ ws)
{
    __shared__ float zs[36 * RS];       // 6x6 z rows   (2448 floats)
    __shared__ float bs[75 * RS];       // 3 fields x 5x5 rows (5100 floats)
    __shared__ float rsc[4][2];

    const int tid  = threadIdx.x;
    const int lane = tid & 63;
    const int w    = tid >> 6;

    // XCD swizzle: contiguous tile range per XCD.
    const int virt = ((blockIdx.x & 7) << 10) | (blockIdx.x >> 3);
    const int bb   = virt >> 12;
    const int rest = virt & 4095;
    const int x0 = ((rest >> 6) & 63) << 2;
    const int y0 = (rest & 63) << 2;

    const float* zg = zin + ((size_t)bb << 22);

    // ---- staging: 36 z rows + 75 b rows, 16 float4 each = 1776 float4 ----
    for (int i = tid; i < 1776; i += 256) {
        int r = i >> 4, o = (i & 15) << 2;
        const float* src;
        float* dst;
        if (r < 36) {
            int xi = r / 6, yr = r - xi * 6;
            int x = x0 - 1 + xi; x = x < 0 ? 0 : (x > 255 ? 255 : x);
            int y = y0 - 1 + yr; y = y < 0 ? 0 : (y > 255 ? 255 : y);
            src = &zg[x * 16384 + y * 64 + o];
            dst = &zs[r * RS + o];
        } else {
            int rr = r - 36;
            int f = rr / 25, rem = rr - f * 25;
            int xi = rem / 5, yr = rem - xi * 5;
            int x = x0 + xi; x = x > 255 ? 255 : x;
            int y = y0 + yr; y = y > 255 ? 255 : y;
            src = &tg[((size_t)(bb * 3 + f) << 22) + x * 16384 + y * 64 + o];
            dst = &bs[rr * RS + o];
        }
        *(float4*)dst = *(const float4*)src;
    }
    __syncthreads();

    // ---- compute: thread = (cell, k-quad) ----
    const int c  = tid >> 4;
    const int kq = tid & 15;
    const int cx = c & 3, cy = c >> 2;
    const int xg = x0 + cx, yg = y0 + cy;
    const int k0 = kq << 2;

    const float* zC = &zs[((cx + 1) * 6 + (cy + 1)) * RS + k0];

    float zcv[7];
    {   // elements k0-1 .. k0+5 (pad/garbage at edges only feeds masked terms)
        float4 a = *(const float4*)zC;
        zcv[0] = zC[-1]; zcv[1] = a.x; zcv[2] = a.y; zcv[3] = a.z; zcv[4] = a.w;
        zcv[5] = zC[4];  zcv[6] = zC[5];
    }
    float zEv[5], zWv[5], zNv[5], zSv[5], zNEv[5];
    ld5(zEv,  zC + 6 * RS);
    ld5(zWv,  zC - 6 * RS);
    ld5(zNv,  zC + RS);
    ld5(zSv,  zC - RS);
    ld5(zNEv, zC + 7 * RS);

    float dz0[4], dzE[4], dzN[4], dzNE[4];
    #pragma unroll
    for (int e = 0; e < 4; ++e) {
        dz0[e]  = zcv[e + 2] - zcv[e + 1];
        dzE[e]  = zEv[e + 1] - zEv[e];
        dzN[e]  = zNv[e + 1] - zNv[e];
        dzNE[e] = zNEv[e + 1] - zNEv[e];
    }
    float s1a[4], s2a[4];
    #pragma unroll
    for (int e = 0; e < 4; ++e) {
        bool kok = (k0 + e) < 63;
        s1a[e] = kok ? dz0[e] : 0.0f;
        s2a[e] = kok ? dz0[e] * dz0[e] : 0.0f;
    }

    float sm = 0.0f;
    if (xg >= 1 && xg <= 254 && yg >= 1 && yg <= 254) {
        #pragma unroll
        for (int e = 0; e < 4; ++e) {
            int k = k0 + e;
            if (k >= 1 && k <= 61) {
                float dzm = zcv[e + 1] - zcv[e];
                float dzp = zcv[e + 3] - zcv[e + 2];
                float dzw = zWv[e + 1] - zWv[e];
                float dzs = zSv[e + 1] - zSv[e];
                float lap = 6.0f * dz0[e] * dz0[e]
                          - dzw * dzw - dzE[e] * dzE[e]
                          - dzs * dzs - dzN[e] * dzN[e]
                          - dzm * dzm - dzp * dzp;
                sm += lap * lap;
            }
        }
    }

    float dv = 0.0f;
    if (xg < 255 && yg < 255) {
        float dCE[5], dCN[5], dENE[5], dNNE[5];
        #pragma unroll
        for (int j = 0; j < 5; ++j) {
            dCE[j]  = zcv[j + 1] - zEv[j];
            dCN[j]  = zcv[j + 1] - zNv[j];
            dENE[j] = zEv[j] - zNEv[j];
            dNNE[j] = zNv[j] - zNEv[j];
        }
        float sxp[4], sxm[4], syp[4], sym[4];
        #pragma unroll
        for (int e = 0; e < 4; ++e) {
            float aC = fabsf(dz0[e]),  aE  = fabsf(dzE[e]);
            float aN = fabsf(dzN[e]),  aNE = fabsf(dzNE[e]);
            sxp[e] = aE + aNE;  sxm[e] = aC + aN;
            syp[e] = aN + aNE;  sym[e] = aC + aE;
        }

        const float* bP = &bs[(cx * 5 + cy) * RS + k0];   // bx corner 00
        const float c6 = 1.0f / 6.0f;
        float num[4], den[4];

        // -- bx --  (telescoping g)
        {
            float A00[5], A10[5], A01[5], A11[5];
            ld5(A00, bP);                ld5(A10, bP + 5 * RS);
            ld5(A01, bP + RS);           ld5(A11, bP + 6 * RS);
            float qx[5], px2[5], g[5];
            #pragma unroll
            for (int j = 0; j < 5; ++j) {
                qx[j]  = A10[j] + A11[j];
                px2[j] = A00[j] + A01[j];
                g[j]   = (qx[j] + A00[j]) * dCE[j] + (qx[j] + A01[j]) * dNNE[j];
            }
            #pragma unroll
            for (int e = 0; e < 4; ++e) {
                float qq = qx[e] + qx[e + 1], pp = px2[e] + px2[e + 1];
                num[e] = 0.125f * (qq * sxp[e] - pp * sxm[e]) + c6 * (g[e + 1] - g[e]);
                float s = qq + pp;
                den[e] = s * s;
            }
        }
        // -- by --  (telescoping h)
        {
            const float* bQ = bP + 25 * RS;
            float A00[5], A10[5], A01[5], A11[5];
            ld5(A00, bQ);                ld5(A10, bQ + 5 * RS);
            ld5(A01, bQ + RS);           ld5(A11, bQ + 6 * RS);
            float qy[5], py2[5], h[5];
            #pragma unroll
            for (int j = 0; j < 5; ++j) {
                qy[j]  = A01[j] + A11[j];
                py2[j] = A00[j] + A10[j];
                h[j]   = (qy[j] + A10[j]) * dENE[j] + (qy[j] + A00[j]) * dCN[j];
            }
            #pragma unroll
            for (int e = 0; e < 4; ++e) {
                float qq = qy[e] + qy[e + 1], pp = py2[e] + py2[e + 1];
                num[e] += 0.125f * (qq * syp[e] - pp * sym[e]) + c6 * (h[e + 1] - h[e]);
                float s = qq + pp;
                den[e] += s * s;
            }
        }
        // -- bz --
        {
            const float* bR = bP + 50 * RS;
            float A00[5], A10[5], A01[5], A11[5];
            ld5(A00, bR);                ld5(A10, bR + 5 * RS);
            ld5(A01, bR + RS);           ld5(A11, bR + 6 * RS);
            float sz[5];
            #pragma unroll
            for (int j = 0; j < 5; ++j)
                sz[j] = A00[j] + A10[j] + A01[j] + A11[j];
            #pragma unroll
            for (int e = 0; e < 4; ++e) {
                num[e] += 0.25f * (sz[e + 1] - sz[e]);
                float s = sz[e] + sz[e + 1];
                den[e] += s * s;
            }
        }
        #pragma unroll
        for (int e = 0; e < 4; ++e) {
            if ((k0 + e) < 63) {
                float d = den[e] * 0.015625f + 1e-10f;
                dv += num[e] * num[e] * __builtin_amdgcn_rcpf(d);
            }
        }
    }

    // ---- block reduction (reuse zs after barrier) ----
    #pragma unroll
    for (int off = 32; off > 0; off >>= 1) {
        sm += __shfl_down(sm, off, 64);
        dv += __shfl_down(dv, off, 64);
    }

    __syncthreads();   // all LDS reads done; safe to reuse zs
    float* r1 = zs;            // 1024 floats
    float* r2 = zs + 1024;     // 1024 floats
    { float4 v; v.x = s1a[0]; v.y = s1a[1]; v.z = s1a[2]; v.w = s1a[3];
      *(float4*)&r1[tid << 2] = v; }
    { float4 v; v.x = s2a[0]; v.y = s2a[1]; v.z = s2a[2]; v.w = s2a[3];
      *(float4*)&r2[tid << 2] = v; }
    if (lane == 0) { rsc[w][0] = sm; rsc[w][1] = dv; }
    __syncthreads();

    if (tid < 64) {
        float a = 0.0f, b2 = 0.0f;
        #pragma unroll
        for (int cc = 0; cc < 16; ++cc) {
            a  += r1[cc * 64 + tid];
            b2 += r2[cc * 64 + tid];
        }
        float* sl = ws + (blockIdx.x & 31) * 258;
        if (tid < 63) {
            atomicAdd(&sl[2 + bb * 64 + tid],   a);
            atomicAdd(&sl[130 + bb * 64 + tid], b2);
        }
        if (tid == 0) atomicAdd(&sl[0], rsc[0][0] + rsc[1][0] + rsc[2][0] + rsc[3][0]);
        if (tid == 1) atomicAdd(&sl[1], rsc[0][1] + rsc[1][1] + rsc[2][1] + rsc[3][1]);
    }
}

__global__ __launch_bounds__(128) void finalize_kernel(const float* __restrict__ ws,
                                                       float* __restrict__ out)
{
    __shared__ double red[128];
    const int t = threadIdx.x;
    double stdv = 0.0;
    {
        int k = t & 63, bb = t >> 6;
        if (k < 63) {
            double s1 = 0.0, s2 = 0.0;
            for (int p = 0; p < 32; ++p) {
                s1 += (double)ws[p * 258 + 2 + bb * 64 + k];
                s2 += (double)ws[p * 258 + 130 + bb * 64 + k];
            }
            const double N = 65536.0;
            double var = (s2 - s1 * s1 / N) / (N - 1.0);
            stdv = sqrt(var > 0.0 ? var : 0.0);
        }
    }
    red[t] = stdv;
    __syncthreads();
    for (int off = 64; off > 0; off >>= 1) {
        if (t < off) red[t] += red[t + off];
        __syncthreads();
    }
    if (t == 0) {
        double smt = 0.0, dvt = 0.0;
        for (int p = 0; p < 32; ++p) {
            smt += (double)ws[p * 258 + 0];
            dvt += (double)ws[p * 258 + 1];
        }
        double loss_std    = red[0] / 126.0;
        double loss_smooth = smt / (2.0 * 254.0 * 254.0 * 61.0);
        double loss_div    = dvt / (2.0 * 255.0 * 255.0 * 63.0);
        out[0] = (float)(loss_div * 1e9);
        out[1] = (float)(loss_smooth * 10.0 + loss_std * 100.0);
    }
}

extern "C" void kernel_launch(void* const* d_in, const int* in_sizes, int n_in,
                              void* d_out, int out_size, void* d_ws, size_t ws_size,
                              hipStream_t stream) {
    const float* z  = (const float*)d_in[0];   // outputs (2,1,256,256,64)
    const float* tg = (const float*)d_in[1];   // targets (2,3,256,256,64)
    float* out = (float*)d_out;
    float* ws  = (float*)d_ws;

    zero_ws_kernel<<<1, 512, 0, stream>>>(ws);
    // 64x64 tiles x 2 batches = 8192 blocks
    fused_loss_kernel<<<8192, 256, 0, stream>>>(z, tg, ws);
    finalize_kernel<<<1, 128, 0, stream>>>(ws, out);
}